// Round 3
// baseline (300.033 us; speedup 1.0000x reference)
//
#include <hip/hip_runtime.h>
#include <hip/hip_cooperative_groups.h>

namespace cg = cooperative_groups;

// Problem constants (from setup_inputs): B=8, N=2048, D=128.
#define BSZ   8
#define NN    2048
#define DD    128
#define NROWS (BSZ * NN)          // 16384
#define N4    (NN / 4)            // 512 float4 per row
#define P_A   0.8f
#define P_B   0.2f

#define BLOCKS 1024               // 4 blocks/CU on 256 CUs -> co-resident (coop)
#define RPB    16                 // rows per block; 2048/16=128 blocks/batch ->
                                  // all 16 rows of a block share one batch b

// Clang native vector type — required by __builtin_nontemporal_load/store.
typedef float v4f __attribute__((ext_vector_type(4)));

// Single cooperative kernel.
// Phase 1: si[row] = dot(x[row], W[0:128]) + bias ; sj[row] = dot(x[row], W[128:256])
//          Each block computes its own 16 rows (4 waves x 4 rows), writes ws.
// grid.sync()
// Phase 2: streaming fuse over this block's 16 contiguous output rows.
//          sj row (8 KB, batch-uniform per block) hoisted into 2 register loads.
__global__ __launch_bounds__(256, 4) void fused_all(const float* __restrict__ x,
                                                    const v4f*  __restrict__ adj,
                                                    const float* __restrict__ W,
                                                    const float* __restrict__ bias,
                                                    float* __restrict__ si,
                                                    float* __restrict__ sj,
                                                    v4f* __restrict__ out) {
    const int tid  = threadIdx.x;
    const int lane = tid & 63;
    const int wave = tid >> 6;                 // 0..3
    const int row0 = blockIdx.x * RPB;         // block's first row

    // ---------------- Phase 1: row dot products (4 rows per wave) ------------
    {
        const float2* W2 = (const float2*)W;
        const float2 wi = W2[lane];            // si weights
        const float2 wj = W2[lane + 64];       // sj weights

        const int r0 = row0 + wave * 4;
        float a_si[4], a_sj[4];
        #pragma unroll
        for (int k = 0; k < 4; ++k) {
            const float2* xr = (const float2*)(x + (size_t)(r0 + k) * DD);
            float2 a = xr[lane];
            a_si[k] = a.x * wi.x + a.y * wi.y;
            a_sj[k] = a.x * wj.x + a.y * wj.y;
        }
        #pragma unroll
        for (int off = 32; off > 0; off >>= 1) {
            #pragma unroll
            for (int k = 0; k < 4; ++k) {
                a_si[k] += __shfl_down(a_si[k], off, 64);
                a_sj[k] += __shfl_down(a_sj[k], off, 64);
            }
        }
        if (lane == 0) {
            float bb = bias[0];
            #pragma unroll
            for (int k = 0; k < 4; ++k) {
                si[r0 + k] = a_si[k] + bb;
                sj[r0 + k] = a_sj[k];
            }
        }
    }

    cg::this_grid().sync();

    // ---------------- Phase 2: streaming fuse --------------------------------
    {
        const int b = row0 >> 11;                      // N = 2048 = 2^11
        const v4f* sjrow = (const v4f*)(sj + (b << 11));
        const v4f sv0 = sjrow[tid];                    // loop-invariant: hoisted
        const v4f sv1 = sjrow[tid + 256];

        #pragma unroll 4
        for (int r = 0; r < RPB; ++r) {
            const int row = row0 + r;                  // uniform -> scalar path
            const float s = si[row];
            const size_t base = (size_t)row * N4;

            v4f av0 = __builtin_nontemporal_load(adj + base + tid);
            v4f av1 = __builtin_nontemporal_load(adj + base + tid + 256);

            v4f o0, o1;
            o0.x = P_A * __builtin_amdgcn_rcpf(1.0f + __expf(-(s + sv0.x))) + P_B * av0.x;
            o0.y = P_A * __builtin_amdgcn_rcpf(1.0f + __expf(-(s + sv0.y))) + P_B * av0.y;
            o0.z = P_A * __builtin_amdgcn_rcpf(1.0f + __expf(-(s + sv0.z))) + P_B * av0.z;
            o0.w = P_A * __builtin_amdgcn_rcpf(1.0f + __expf(-(s + sv0.w))) + P_B * av0.w;
            o1.x = P_A * __builtin_amdgcn_rcpf(1.0f + __expf(-(s + sv1.x))) + P_B * av1.x;
            o1.y = P_A * __builtin_amdgcn_rcpf(1.0f + __expf(-(s + sv1.y))) + P_B * av1.y;
            o1.z = P_A * __builtin_amdgcn_rcpf(1.0f + __expf(-(s + sv1.z))) + P_B * av1.z;
            o1.w = P_A * __builtin_amdgcn_rcpf(1.0f + __expf(-(s + sv1.w))) + P_B * av1.w;

            __builtin_nontemporal_store(o0, out + base + tid);
            __builtin_nontemporal_store(o1, out + base + tid + 256);
        }
    }
}

extern "C" void kernel_launch(void* const* d_in, const int* in_sizes, int n_in,
                              void* d_out, int out_size, void* d_ws, size_t ws_size,
                              hipStream_t stream) {
    const float* x    = (const float*)d_in[0];   // [B,N,D]
    const float* adj  = (const float*)d_in[1];   // [B,N,N]
    const float* W    = (const float*)d_in[2];   // [2D]
    const float* bias = (const float*)d_in[3];   // scalar

    float* si = (float*)d_ws;            // NROWS floats
    float* sj = si + NROWS;              // NROWS floats  (total 128 KiB)
    v4f*   out = (v4f*)d_out;
    const v4f* adjv = (const v4f*)adj;

    void* args[] = {(void*)&x, (void*)&adjv, (void*)&W, (void*)&bias,
                    (void*)&si, (void*)&sj, (void*)&out};
    hipLaunchCooperativeKernel((void*)fused_all, dim3(BLOCKS), dim3(256),
                               args, 0, stream);
}

// Round 4
// 238.545 us; speedup vs baseline: 1.2578x; 1.2578x over previous
//
#include <hip/hip_runtime.h>

// Problem constants (from setup_inputs): B=8, N=2048, D=128.
#define BSZ   8
#define NN    2048
#define DD    128
#define NROWS (BSZ * NN)          // 16384
#define N4    (NN / 4)            // 512 float4 per row
#define P_A   0.8f
#define P_B   0.2f

// Kernel 1: per-row dot products.
// si[row] = dot(x[row], W[0:128]) + bias ; sj[row] = dot(x[row], W[128:256])
// One 64-lane wave per row; each lane handles 2 of the 128 elements.
__global__ __launch_bounds__(256) void row_dots(const float* __restrict__ x,
                                                const float* __restrict__ W,
                                                const float* __restrict__ bias,
                                                float* __restrict__ si,
                                                float* __restrict__ sj) {
    int gtid = blockIdx.x * blockDim.x + threadIdx.x;
    int row  = gtid >> 6;         // wave index = row
    int lane = threadIdx.x & 63;
    if (row >= NROWS) return;

    const float* xr = x + (size_t)row * DD;
    float x0 = xr[lane];
    float x1 = xr[lane + 64];

    float a = x0 * W[lane]       + x1 * W[lane + 64];    // si part
    float c = x0 * W[lane + 128] + x1 * W[lane + 192];   // sj part

    // 64-lane butterfly reduction
    #pragma unroll
    for (int off = 32; off > 0; off >>= 1) {
        a += __shfl_down(a, off, 64);
        c += __shfl_down(c, off, 64);
    }
    if (lane == 0) {
        si[row] = a + bias[0];
        sj[row] = c;
    }
}

// Kernel 2: streaming fuse. One thread per float4 of the [B,N,N] output.
__global__ __launch_bounds__(256) void fuse_kernel(const float4* __restrict__ adj,
                                                   const float*  __restrict__ si,
                                                   const float4* __restrict__ sj,
                                                   float4* __restrict__ out) {
    int idx = blockIdx.x * blockDim.x + threadIdx.x;   // [0, B*N*N/4)
    // idx layout: row-major over (b, i, j4)
    int j4  = idx & (N4 - 1);       // j quad within row
    int row = idx >> 9;             // b*N + i   (N4 = 512 = 2^9)
    int b   = row >> 11;            // N = 2048 = 2^11

    float  s   = si[row];                       // wave-uniform-ish broadcast
    float4 sv  = sj[(b << 9) + j4];             // coalesced across lanes
    float4 av  = adj[idx];                      // coalesced stream

    float t0 = s + sv.x;
    float t1 = s + sv.y;
    float t2 = s + sv.z;
    float t3 = s + sv.w;

    float4 o;
    o.x = P_A * (1.0f / (1.0f + __expf(-t0))) + P_B * av.x;
    o.y = P_A * (1.0f / (1.0f + __expf(-t1))) + P_B * av.y;
    o.z = P_A * (1.0f / (1.0f + __expf(-t2))) + P_B * av.z;
    o.w = P_A * (1.0f / (1.0f + __expf(-t3))) + P_B * av.w;

    out[idx] = o;
}

extern "C" void kernel_launch(void* const* d_in, const int* in_sizes, int n_in,
                              void* d_out, int out_size, void* d_ws, size_t ws_size,
                              hipStream_t stream) {
    const float* x    = (const float*)d_in[0];   // [B,N,D]
    const float* adj  = (const float*)d_in[1];   // [B,N,N]
    const float* W    = (const float*)d_in[2];   // [2D]
    const float* bias = (const float*)d_in[3];   // scalar

    float* si = (float*)d_ws;            // NROWS floats
    float* sj = si + NROWS;              // NROWS floats  (total 128 KiB)

    // Kernel 1: 16384 rows, 4 waves (256 threads) per block -> 4096 blocks
    row_dots<<<NROWS / 4, 256, 0, stream>>>(x, W, bias, si, sj);

    // Kernel 2: B*N*N/4 float4 threads
    const int total4 = BSZ * NN * NN / 4;        // 8,388,608
    fuse_kernel<<<total4 / 256, 256, 0, stream>>>(
        (const float4*)adj, si, (const float4*)sj, (float4*)d_out);
}